// Round 13
// baseline (1017.986 us; speedup 1.0000x reference)
//
#include <hip/hip_runtime.h>
#include <math.h>

// Problem constants
#define B_  16
#define L_  128
#define E_  34
#define A_  36
#define D_  300
#define H_  256
#define KP_ 320     // D padded to mult of 32 (bf16 MFMA K)
#define G4_ 1024    // 4*H
#define KC_ 512     // 2*H
#define NCAT_ 128   // padded 36(base)+36(trig)+34(evh)
#define WAS_ 1092   // Wa row stride = 4H + A-1 + E-1
#define WES_ 545    // We row stride = 2H + E-1

// Workspace layout (float offsets)
#define O_HX     1310720u   // u64[2][64][128] tagged h exchange (parity dbuf)
#define O_BSUM_F 1343488u   // [1024] bih+bhh
#define O_BSUM_B 1344512u
#define O_ZPRE   1345536u   // [2][128][16][1024]  x@WihT + bias, in processing order
#define O_HIDDEN 5539840u   // [128][16][512]  hs-layout (t,b), fwd [0:256), bwd [256:512)
#define O_WCAT   6588416u   // [512][128]  cols: 0..35 Wa_hidden, 36..71 Wa_trig, 72..105 We_hidden
#define O_BVEC   6653952u   // [128]       ba | 0 | be
#define O_P      6654080u   // [2048][128] hidden @ Wcat + bvec   (rows m = t*16+b)
#define O_EVTAG  6916224u   // int [16][128]  self-tagged event preds ((i+1)<<8 | p)

#define HIX(k) ((k) + (((k) >> 5) << 2))   // +4 float pad per 32 to stagger banks

// lgkm-only barrier: skips the vmcnt(0) store-ack/prefetch drain __syncthreads emits.
// Safe when the barrier only orders LDS traffic (global deps handled by data deps).
#define BARRIER_LGKM() asm volatile("s_waitcnt lgkmcnt(0)\n\ts_barrier" ::: "memory")

typedef short bf16x8 __attribute__((ext_vector_type(8)));
typedef float f32x4  __attribute__((ext_vector_type(4)));

__device__ __forceinline__ float fsig(float x) {
    return __builtin_amdgcn_rcpf(1.0f + __expf(-x));
}
__device__ __forceinline__ float ftanh(float x) {
    float e = __expf(-2.0f * fabsf(x));          // (0,1] - no overflow
    float t = (1.0f - e) * __builtin_amdgcn_rcpf(1.0f + e);
    return copysignf(t, x);
}
__device__ __forceinline__ unsigned short f2bf(float f) {   // RNE f32->bf16
    unsigned u = __float_as_uint(f);
    return (unsigned short)((u + 0x7fffu + ((u >> 16) & 1u)) >> 16);
}
__device__ __forceinline__ float bf2f(unsigned short h) {
    return __uint_as_float(((unsigned)h) << 16);
}

// ---------------------------------------------------------------- prep (tiny)
__global__ void k_prep(const float* __restrict__ bih_f, const float* __restrict__ bhh_f,
                       const float* __restrict__ bih_b, const float* __restrict__ bhh_b,
                       const float* __restrict__ We, const float* __restrict__ be,
                       const float* __restrict__ Wa, const float* __restrict__ ba,
                       float* __restrict__ ws) {
    const int N3 = 2 * 1024;     // bsum
    const int N4 = 65536;        // Wcat
    const int N5 = 128;          // bvec
    const int total = N3 + N4 + N5;
    for (int idx = blockIdx.x * blockDim.x + threadIdx.x; idx < total;
         idx += gridDim.x * blockDim.x) {
        int i = idx;
        if (i < N3) {
            int dir = i / 1024, r = i % 1024;
            ws[(dir ? O_BSUM_B : O_BSUM_F) + r] =
                (dir ? bih_b[r] + bhh_b[r] : bih_f[r] + bhh_f[r]);
            continue;
        }
        i -= N3;
        if (i < N4) {
            int k = i >> 7, n = i & 127;
            float v = 0.0f;
            if (n < 36)               v = Wa[n * WAS_ + k];
            else if (n < 72)          v = Wa[(n - 36) * WAS_ + KC_ + k];
            else if (n < 106)         v = We[(n - 72) * WES_ + k];
            ws[O_WCAT + i] = v;
            continue;
        }
        i -= N4;
        {
            float v = 0.0f;
            if (i < 36)               v = ba[i];
            else if (i >= 72 && i < 106) v = be[i - 72];
            ws[O_BVEC + i] = v;
        }
    }
}

// ------------------------------------------------- GEMM1 (MFMA bf16x3): z = x @ WihT + bsum
// 128x128 tile, 4 waves (2x2 of 64x64), mfma_f32_16x16x32_bf16, K=320 in 10 steps.
// SPLIT PRECISION: z = Xh*Wh + Xh*Wl + Xl*Wh (lo*lo omitted, ~1e-7 RMS) -- verified
// PASS at absmax 0.0039 (r5/r7/r10/r11/r12). Reads emb (ids-gathered) and Wih fp32
// DIRECTLY, casting hi/lo in-register while staging.
__global__ __launch_bounds__(256) void k_gemm1(const int* __restrict__ ids,
                                               const float* __restrict__ emb,
                                               const float* __restrict__ Wih_f,
                                               const float* __restrict__ Wih_b,
                                               float* __restrict__ ws) {
    __shared__ unsigned short Ah[128][40];
    __shared__ unsigned short Al[128][40];
    __shared__ unsigned short Bh[128][40];
    __shared__ unsigned short Bl[128][40];
    int dir = blockIdx.z;
    int m0 = blockIdx.y * 128;
    int n0 = blockIdx.x * 128;
    int tid = threadIdx.x;
    const float* bsv = ws + (dir ? O_BSUM_B : O_BSUM_F);

    int w = tid >> 6, lane = tid & 63;
    int wr = w >> 1, wc = w & 1;
    int lr = lane & 15, lk = lane >> 4;

    // staging: thread t -> LDS row t>>1, 16 elems at half (t&1)
    int sr = tid >> 1, sh = tid & 1;
    int gm = m0 + sr;
    int tt = gm >> 4, bb2 = gm & 15;
    int t_orig = dir ? (L_ - 1 - tt) : tt;
    int aid = ids[bb2 * L_ + t_orig];
    const float* arow = emb + (size_t)aid * D_;
    const float* brow = (dir ? Wih_b : Wih_f) + (size_t)(n0 + sr) * D_;
    int swb = sr * 80 + sh * 32;

    f32x4 acc[4][4] = {};
    for (int k0 = 0; k0 < KP_; k0 += 32) {
        int c0 = k0 + sh * 16;
        float fa[16], fb[16];
        if (c0 + 16 <= D_) {
#pragma unroll
            for (int q = 0; q < 4; q++) {
                float4 va = *(const float4*)(arow + c0 + q * 4);
                float4 vb = *(const float4*)(brow + c0 + q * 4);
                fa[q * 4 + 0] = va.x; fa[q * 4 + 1] = va.y;
                fa[q * 4 + 2] = va.z; fa[q * 4 + 3] = va.w;
                fb[q * 4 + 0] = vb.x; fb[q * 4 + 1] = vb.y;
                fb[q * 4 + 2] = vb.z; fb[q * 4 + 3] = vb.w;
            }
        } else {
#pragma unroll
            for (int e = 0; e < 16; e++) {
                int c = c0 + e;
                fa[e] = (c < D_) ? arow[c] : 0.0f;
                fb[e] = (c < D_) ? brow[c] : 0.0f;
            }
        }
        bf16x8 ah0, ah1, al0, al1, bh0, bh1, bl0, bl1;
#pragma unroll
        for (int e = 0; e < 8; e++) {
            unsigned short h;
            h = f2bf(fa[e]);     ah0[e] = (short)h; al0[e] = (short)f2bf(fa[e] - bf2f(h));
            h = f2bf(fa[e + 8]); ah1[e] = (short)h; al1[e] = (short)f2bf(fa[e + 8] - bf2f(h));
            h = f2bf(fb[e]);     bh0[e] = (short)h; bl0[e] = (short)f2bf(fb[e] - bf2f(h));
            h = f2bf(fb[e + 8]); bh1[e] = (short)h; bl1[e] = (short)f2bf(fb[e + 8] - bf2f(h));
        }
        *(bf16x8*)((char*)&Ah[0][0] + swb) = ah0;
        *(bf16x8*)((char*)&Ah[0][0] + swb + 16) = ah1;
        *(bf16x8*)((char*)&Al[0][0] + swb) = al0;
        *(bf16x8*)((char*)&Al[0][0] + swb + 16) = al1;
        *(bf16x8*)((char*)&Bh[0][0] + swb) = bh0;
        *(bf16x8*)((char*)&Bh[0][0] + swb + 16) = bh1;
        *(bf16x8*)((char*)&Bl[0][0] + swb) = bl0;
        *(bf16x8*)((char*)&Bl[0][0] + swb + 16) = bl1;
        __syncthreads();
        bf16x8 afh[4], afl[4], bfh[4], bfl[4];
#pragma unroll
        for (int mi = 0; mi < 4; mi++) {
            int rb = (wr * 64 + mi * 16 + lr) * 80 + lk * 16;
            afh[mi] = *(const bf16x8*)((const char*)&Ah[0][0] + rb);
            afl[mi] = *(const bf16x8*)((const char*)&Al[0][0] + rb);
        }
#pragma unroll
        for (int ni = 0; ni < 4; ni++) {
            int rb = (wc * 64 + ni * 16 + lr) * 80 + lk * 16;
            bfh[ni] = *(const bf16x8*)((const char*)&Bh[0][0] + rb);
            bfl[ni] = *(const bf16x8*)((const char*)&Bl[0][0] + rb);
        }
#pragma unroll
        for (int mi = 0; mi < 4; mi++)
#pragma unroll
            for (int ni = 0; ni < 4; ni++) {
                acc[mi][ni] = __builtin_amdgcn_mfma_f32_16x16x32_bf16(
                    afh[mi], bfh[ni], acc[mi][ni], 0, 0, 0);
                acc[mi][ni] = __builtin_amdgcn_mfma_f32_16x16x32_bf16(
                    afh[mi], bfl[ni], acc[mi][ni], 0, 0, 0);
                acc[mi][ni] = __builtin_amdgcn_mfma_f32_16x16x32_bf16(
                    afl[mi], bfh[ni], acc[mi][ni], 0, 0, 0);
            }
        __syncthreads();
    }
    float* zp = ws + O_ZPRE + (size_t)dir * 2048 * G4_;
    int crow = (lane >> 4) * 4;
#pragma unroll
    for (int ni = 0; ni < 4; ni++) {
        int n = n0 + wc * 64 + ni * 16 + lr;
        float bias = bsv[n];
#pragma unroll
        for (int mi = 0; mi < 4; mi++) {
            int mb = m0 + wr * 64 + mi * 16 + crow;
#pragma unroll
            for (int j = 0; j < 4; j++)
                zp[(size_t)(mb + j) * G4_ + n] = acc[mi][ni][j] + bias;
        }
    }
}

// ------------------------------------------------- LSTM: 64 blocks x 1024 threads
// (2 blocks per chain instead of 4 -- this revision). phys = g*32 + (dir*16+b),
// g in {0,1}: block owns h[g*128:(g+1)*128) = 512 gate rows; weights stay at
// 128 floats/thread (same VGPR as the 4-block form). Exchange fan-in drops from
// 3 sibling polls (192 u64) to ONE sibling (phys^32, 128 u64): removes the
// max-of-3 publish-jitter per step and halves MALL publish traffic. Sibling
// pairs differ by 32 == 0 (mod 8) -> likely same XCD (speed heuristic only;
// correctness stays on the proven agent/MALL tagged-u64 parity-dbuf protocol:
// publish-first + s_sleep(10) phase alignment (r7/r11/r12 gradient), lgkm-only
// barriers, WAR-safe single h_sh).
// Thread map: rg = tid>>3 (4 consecutive gate rows of one gate: gate = lr0>>7,
// offset = lr0&127), kc = tid&7 (32-wide k chunk). Activation: tid<128 (2 waves,
// coalesced 128-u64 publish). Pollers: tid in [128,256).
__global__ __launch_bounds__(1024, 1) void k_lstm(float* __restrict__ ws,
                                                  const float* __restrict__ Whh_f,
                                                  const float* __restrict__ Whh_b) {
    int phys = blockIdx.x;           // 0..63
    int g    = phys >> 5;            // 0..1: which h-half this block owns
    int cb   = phys & 31;
    int b    = cb & 15;
    int dir  = cb >> 4;
    int tid  = threadIdx.x;
    int rg   = tid >> 3;             // 0..127 -> 4 consecutive gate rows
    int kc   = tid & 7;              // 0..7  -> k chunk of 32

    const float* Whh  = dir ? Whh_b : Whh_f;
    const float* zpre = ws + O_ZPRE + (size_t)dir * 2048 * G4_;
    float* hid = ws + O_HIDDEN;
    unsigned long long* hx64 = (unsigned long long*)(ws + O_HX);

    __shared__ float h_sh[HIX(255) + 1 + 4];
    __shared__ float zbuf[512];

    int lr0  = rg << 2;                                   // local gate-row 0..508
    int ggr0 = (lr0 >> 7) * 256 + g * 128 + (lr0 & 127);  // global gate row (i,f,g,o blocks)
    float4 w[4][8];
#pragma unroll
    for (int i = 0; i < 4; i++) {
        const float* wr = Whh + (size_t)(ggr0 + i) * H_ + (kc << 5);
#pragma unroll
        for (int c = 0; c < 8; c++) w[i][c] = *(const float4*)(wr + (c << 2));
    }
    for (int k = tid; k < HIX(255) + 1 + 4; k += 1024) h_sh[k] = 0.0f;
    float c_state = 0.0f;
    float4 zv = make_float4(0.f, 0.f, 0.f, 0.f);
    if (kc == 0) zv = *(const float4*)(zpre + (size_t)(0 * B_ + b) * G4_ + ggr0);
    __syncthreads();

    for (int s = 0; s < L_; s++) {
        float4 zn = make_float4(0.f, 0.f, 0.f, 0.f);
        if (kc == 0 && s + 1 < L_)
            zn = *(const float4*)(zpre + (size_t)((s + 1) * B_ + b) * G4_ + ggr0);
        float a0 = 0.f, a1 = 0.f, a2 = 0.f, a3 = 0.f;
        const float* hp = &h_sh[kc * 36];
#pragma unroll
        for (int c = 0; c < 8; c++) {
            float4 hv = *(const float4*)(hp + (c << 2));
            a0 = fmaf(w[0][c].x, hv.x, a0); a0 = fmaf(w[0][c].y, hv.y, a0);
            a0 = fmaf(w[0][c].z, hv.z, a0); a0 = fmaf(w[0][c].w, hv.w, a0);
            a1 = fmaf(w[1][c].x, hv.x, a1); a1 = fmaf(w[1][c].y, hv.y, a1);
            a1 = fmaf(w[1][c].z, hv.z, a1); a1 = fmaf(w[1][c].w, hv.w, a1);
            a2 = fmaf(w[2][c].x, hv.x, a2); a2 = fmaf(w[2][c].y, hv.y, a2);
            a2 = fmaf(w[2][c].z, hv.z, a2); a2 = fmaf(w[2][c].w, hv.w, a2);
            a3 = fmaf(w[3][c].x, hv.x, a3); a3 = fmaf(w[3][c].y, hv.y, a3);
            a3 = fmaf(w[3][c].z, hv.z, a3); a3 = fmaf(w[3][c].w, hv.w, a3);
        }
#pragma unroll
        for (int m = 1; m < 8; m <<= 1) {
            a0 += __shfl_xor(a0, m); a1 += __shfl_xor(a1, m);
            a2 += __shfl_xor(a2, m); a3 += __shfl_xor(a3, m);
        }
        if (kc == 0) {
            float4 z4;
            z4.x = a0 + zv.x; z4.y = a1 + zv.y; z4.z = a2 + zv.z; z4.w = a3 + zv.w;
            *(float4*)&zbuf[lr0] = z4;
        }
        zv = zn;
        BARRIER_LGKM();
        int par = (s + 1) & 1;
        if (tid < 128) {
            float fi = fsig(zbuf[tid]);          // gate i rows: local 0..127
            float ff = fsig(zbuf[tid + 128]);    // gate f
            float gg = ftanh(zbuf[tid + 256]);   // gate g
            float fo = fsig(zbuf[tid + 384]);    // gate o
            c_state = ff * c_state + fi * gg;
            float h = fo * ftanh(c_state);
            int hr = g * 128 + tid;
            // publish FIRST: visibility latency is the critical path
            if (s + 1 < L_) {
                unsigned long long pk =
                    ((unsigned long long)(unsigned)(s + 1) << 32) | (unsigned)__float_as_uint(h);
                __hip_atomic_store(&hx64[(par << 13) + (phys << 7) + tid], pk,
                                   __ATOMIC_RELAXED, __HIP_MEMORY_SCOPE_AGENT);
            }
            h_sh[HIX(hr)] = h;
            int t_orig = dir ? (L_ - 1 - s) : s;
            hid[(size_t)(t_orig * B_ + b) * KC_ + dir * H_ + hr] = h;
        }
        if (tid >= 128 && tid < 256 && s + 1 < L_) {
            int u  = tid - 128;                  // 0..127
            int sb = phys ^ 32;                  // the ONE sibling block
            const unsigned long long* wp = &hx64[(par << 13) + (sb << 7) + u];
            unsigned long long v;
            int cnt = 0;
            // phase-align the first poll with publish visibility
            __builtin_amdgcn_s_sleep(10);
            do {
                v = __hip_atomic_load(wp, __ATOMIC_RELAXED, __HIP_MEMORY_SCOPE_AGENT);
            } while ((int)(v >> 32) < s + 1 && ++cnt < (1 << 20));
            h_sh[HIX((g ^ 1) * 128 + u)] = __uint_as_float((unsigned)v);
        }
        BARRIER_LGKM();
    }
}

// ------------------------------------------------- GEMM2: P = hidden @ Wcat + bvec
__global__ __launch_bounds__(256) void k_gemm2(float* __restrict__ ws) {
    __shared__ float As[16][64];
    __shared__ float Bs[16][64];
    int m0 = blockIdx.y * 64;
    int n0 = blockIdx.x * 64;
    int tid = threadIdx.x;
    const float* Ap = ws + O_HIDDEN;
    const float* Bp = ws + O_WCAT;
    const float* bv = ws + O_BVEC;
    float acc[4][4] = {};
    int a_m = tid >> 2, a_k = (tid & 3) << 2;
    int b_k = tid >> 4, b_n = (tid & 15) << 2;
    int ty = tid >> 4, tx = tid & 15;
    const float* arow = Ap + (size_t)(m0 + a_m) * KC_;
    for (int k0 = 0; k0 < KC_; k0 += 16) {
        float4 av = *(const float4*)(arow + k0 + a_k);
        float4 bvv = *(const float4*)(Bp + (size_t)(k0 + b_k) * NCAT_ + n0 + b_n);
        As[a_k + 0][a_m] = av.x; As[a_k + 1][a_m] = av.y;
        As[a_k + 2][a_m] = av.z; As[a_k + 3][a_m] = av.w;
        *(float4*)&Bs[b_k][b_n] = bvv;
        __syncthreads();
#pragma unroll
        for (int kk = 0; kk < 16; kk++) {
            float4 a4 = *(const float4*)&As[kk][ty * 4];
            float4 b4 = *(const float4*)&Bs[kk][tx * 4];
            acc[0][0] = fmaf(a4.x, b4.x, acc[0][0]); acc[0][1] = fmaf(a4.x, b4.y, acc[0][1]);
            acc[0][2] = fmaf(a4.x, b4.z, acc[0][2]); acc[0][3] = fmaf(a4.x, b4.w, acc[0][3]);
            acc[1][0] = fmaf(a4.y, b4.x, acc[1][0]); acc[1][1] = fmaf(a4.y, b4.y, acc[1][1]);
            acc[1][2] = fmaf(a4.y, b4.z, acc[1][2]); acc[1][3] = fmaf(a4.y, b4.w, acc[1][3]);
            acc[2][0] = fmaf(a4.z, b4.x, acc[2][0]); acc[2][1] = fmaf(a4.z, b4.y, acc[2][1]);
            acc[2][2] = fmaf(a4.z, b4.z, acc[2][2]); acc[2][3] = fmaf(a4.z, b4.w, acc[2][3]);
            acc[3][0] = fmaf(a4.w, b4.x, acc[3][0]); acc[3][1] = fmaf(a4.w, b4.y, acc[3][1]);
            acc[3][2] = fmaf(a4.w, b4.z, acc[3][2]); acc[3][3] = fmaf(a4.w, b4.w, acc[3][3]);
        }
        __syncthreads();
    }
    float4 bias = *(const float4*)(bv + n0 + tx * 4);
    float* Pp = ws + O_P + (size_t)m0 * NCAT_;
#pragma unroll
    for (int i = 0; i < 4; i++) {
        float4 o;
        o.x = acc[i][0] + bias.x; o.y = acc[i][1] + bias.y;
        o.z = acc[i][2] + bias.z; o.w = acc[i][3] + bias.w;
        *(float4*)(Pp + (size_t)(ty * 4 + i) * NCAT_ + n0 + tx * 4) = o;
    }
}

// ------------------------------------------------- fused decoder (r10 form)
// block 0: event chains (16 waves), publishes self-tagged preds evtag[b][i] = ((i+1)<<8)|p;
//   depth-3 P-row prefetch (r10: -5us).
// blocks 1..128: 16 argument chains each; tag reads amortized via a cached 64-slot
// window (ONE agent load per 64 steps per lane + shfl). Tag polls use s_sleep
// backoff on miss. Arg chains keep depth-2 (wave parallelism hides their latency).
__global__ __launch_bounds__(1024) void k_dec(const float* __restrict__ We,
                                              const float* __restrict__ Wa,
                                              float* __restrict__ ws, float* __restrict__ out) {
    const float* P = ws + O_P;
    int* evtag = (int*)(ws + O_EVTAG);   // [16][128]
    int lane = threadIdx.x & 63;
    if (blockIdx.x == 0) {
        int b = threadIdx.x >> 6;
        float Cg = 0.0f;
        unsigned long long gmask = 0ull;
        float pv = (lane < E_) ? P[(size_t)(0 * B_ + b) * NCAT_ + 72 + lane] : 0.0f;
        float p1 = (lane < E_) ? P[(size_t)(1 * B_ + b) * NCAT_ + 72 + lane] : 0.0f;
        float p2 = (lane < E_) ? P[(size_t)(2 * B_ + b) * NCAT_ + 72 + lane] : 0.0f;
        for (int i = 0; i < L_; i++) {
            float p3 = 0.0f;
            if (i + 3 < L_ && lane < E_) p3 = P[(size_t)((i + 3) * B_ + b) * NCAT_ + 72 + lane];
            float v = (lane < E_) ? (pv + Cg) : -INFINITY;
            float mv = v;
            int mi = (lane < E_) ? lane : 0x7fffffff;
#pragma unroll
            for (int off = 32; off; off >>= 1) {
                float ov = __shfl_down(mv, off);
                int oi = __shfl_down(mi, off);
                if (ov > mv || (ov == mv && oi < mi)) { mv = ov; mi = oi; }
            }
            int p = __shfl(mi, 0);
            if (lane == 0)
                __hip_atomic_store(&evtag[b * L_ + i], ((i + 1) << 8) | p,
                                   __ATOMIC_RELAXED, __HIP_MEMORY_SCOPE_AGENT);
            if (lane < E_) out[(size_t)(b * L_ + i) * E_ + lane] = v;
            if (p > 0) {
                unsigned long long bit = 1ull << (p - 1);
                if (!(gmask & bit)) {
                    gmask |= bit;
                    if (lane < E_) Cg += We[lane * WES_ + 2 * H_ + (p - 1)];
                }
            }
            pv = p1; p1 = p2; p2 = p3;
        }
    } else {
        int w = ((blockIdx.x - 1) << 4) + (threadIdx.x >> 6);  // 0..2047
        int b = w >> 7, j = w & 127;
        float* outa = out + (size_t)B_ * L_ * E_;
        float C = 0.0f;
        if (lane < A_) C = P[(size_t)(j * B_ + b) * NCAT_ + lane];
        unsigned long long ga = 0ull, gta = 0ull;
        float tv = (lane < A_) ? P[(size_t)(0 * B_ + b) * NCAT_ + 36 + lane] : 0.0f;
        float t1 = (lane < A_) ? P[(size_t)(1 * B_ + b) * NCAT_ + 36 + lane] : 0.0f;
        int myv = (int)0x80000000;   // cached tag word for window slot `lane`
        for (int i = 0; i < L_; i++) {
            float t2 = 0.0f;
            if (i + 2 < L_ && lane < A_) t2 = P[(size_t)((i + 2) * B_ + b) * NCAT_ + 36 + lane];
            int w0 = i & ~63;
            if ((i & 63) == 0)
                myv = __hip_atomic_load(&evtag[b * L_ + w0 + lane],
                                        __ATOMIC_RELAXED, __HIP_MEMORY_SCOPE_AGENT);
            int tv_tag = __shfl(myv, i & 63);
            if ((tv_tag >> 8) < i + 1) {   // wave-uniform miss: backoff poll
                int cnt = 0;
                do {
                    __builtin_amdgcn_s_sleep(1);
                    myv = __hip_atomic_load(&evtag[b * L_ + w0 + lane],
                                            __ATOMIC_RELAXED, __HIP_MEMORY_SCOPE_AGENT);
                    tv_tag = __shfl(myv, i & 63);
                } while ((tv_tag >> 8) < i + 1 && ++cnt < (1 << 18));
            }
            int ev = tv_tag & 0xff;
            float v = (lane < A_) ? (C + tv) : -INFINITY;
            float mv = v;
            int mi = (lane < A_) ? lane : 0x7fffffff;
#pragma unroll
            for (int off = 32; off; off >>= 1) {
                float ov = __shfl_down(mv, off);
                int oi = __shfl_down(mi, off);
                if (ov > mv || (ov == mv && oi < mi)) { mv = ov; mi = oi; }
            }
            int p = __shfl(mi, 0);
            if (lane < A_) outa[(size_t)((b * L_ + i) * L_ + j) * A_ + lane] = v;
            if (ev > 0 && p > 0) {
                unsigned long long bq = 1ull << (ev - 1);
                if (!(gta & bq)) {
                    gta |= bq;
                    if (lane < A_) C += Wa[lane * WAS_ + 4 * H_ + A_ - 1 + (ev - 1)];
                }
                unsigned long long br = 1ull << (p - 1);
                if (!(ga & br)) {
                    ga |= br;
                    if (lane < A_) C += Wa[lane * WAS_ + 4 * H_ + (p - 1)];
                }
            }
            tv = t1; t1 = t2;
        }
    }
}

// ----------------------------------------------------------------
extern "C" void kernel_launch(void* const* d_in, const int* in_sizes, int n_in,
                              void* d_out, int out_size, void* d_ws, size_t ws_size,
                              hipStream_t stream) {
    (void)in_sizes; (void)n_in; (void)out_size; (void)ws_size;
    const int*   ids   = (const int*)d_in[0];
    const float* emb   = (const float*)d_in[1];
    const float* Wih_f = (const float*)d_in[2];
    const float* Whh_f = (const float*)d_in[3];
    const float* bih_f = (const float*)d_in[4];
    const float* bhh_f = (const float*)d_in[5];
    const float* Wih_b = (const float*)d_in[6];
    const float* Whh_b = (const float*)d_in[7];
    const float* bih_b = (const float*)d_in[8];
    const float* bhh_b = (const float*)d_in[9];
    const float* We    = (const float*)d_in[10];
    const float* be    = (const float*)d_in[11];
    const float* Wa    = (const float*)d_in[12];
    const float* ba    = (const float*)d_in[13];
    float* out = (float*)d_out;
    float* ws  = (float*)d_ws;

    hipLaunchKernelGGL(k_prep, dim3(64), dim3(256), 0, stream,
                       bih_f, bhh_f, bih_b, bhh_b, We, be, Wa, ba, ws);
    hipLaunchKernelGGL(k_gemm1, dim3(8, 16, 2), dim3(256), 0, stream,
                       ids, emb, Wih_f, Wih_b, ws);
    hipLaunchKernelGGL(k_lstm, dim3(64), dim3(1024), 0, stream, ws, Whh_f, Whh_b);
    hipLaunchKernelGGL(k_gemm2, dim3(2, 32, 1), dim3(256), 0, stream, ws);
    hipLaunchKernelGGL(k_dec, dim3(129), dim3(1024), 0, stream, We, Wa, ws, out);
}

// Round 14
// 482.933 us; speedup vs baseline: 2.1079x; 2.1079x over previous
//
#include <hip/hip_runtime.h>
#include <math.h>

// Problem constants
#define B_  16
#define L_  128
#define E_  34
#define A_  36
#define D_  300
#define H_  256
#define KP_ 320     // D padded to mult of 32 (bf16 MFMA K)
#define G4_ 1024    // 4*H
#define KC_ 512     // 2*H
#define NCAT_ 128   // padded 36(base)+36(trig)+34(evh)
#define WAS_ 1092   // Wa row stride = 4H + A-1 + E-1
#define WES_ 545    // We row stride = 2H + E-1

// Workspace layout (float offsets)
#define O_HX     1310720u   // u64[2][128][64] tagged h exchange (parity dbuf)
#define O_BSUM_F 1343488u   // [1024] bih+bhh
#define O_BSUM_B 1344512u
#define O_ZPRE   1345536u   // [2][128][16][1024]  x@WihT + bias, in processing order
#define O_HIDDEN 5539840u   // [128][16][512]  hs-layout (t,b), fwd [0:256), bwd [256:512)
#define O_WCAT   6588416u   // [512][128]  cols: 0..35 Wa_hidden, 36..71 Wa_trig, 72..105 We_hidden
#define O_BVEC   6653952u   // [128]       ba | 0 | be
#define O_P      6654080u   // [2048][128] hidden @ Wcat + bvec   (rows m = t*16+b)
#define O_EVTAG  6916224u   // int [16][128]  self-tagged event preds ((i+1)<<8 | p)

#define HIX(k) ((k) + (((k) >> 5) << 2))   // +4 float pad per 32 to stagger banks

// lgkm-only barrier: skips the vmcnt(0) store-ack/prefetch drain __syncthreads emits.
// Safe when the barrier only orders LDS traffic (global deps handled by data deps).
#define BARRIER_LGKM() asm volatile("s_waitcnt lgkmcnt(0)\n\ts_barrier" ::: "memory")

typedef short bf16x8 __attribute__((ext_vector_type(8)));
typedef float f32x4  __attribute__((ext_vector_type(4)));

__device__ __forceinline__ float fsig(float x) {
    return __builtin_amdgcn_rcpf(1.0f + __expf(-x));
}
__device__ __forceinline__ float ftanh(float x) {
    float e = __expf(-2.0f * fabsf(x));          // (0,1] - no overflow
    float t = (1.0f - e) * __builtin_amdgcn_rcpf(1.0f + e);
    return copysignf(t, x);
}
__device__ __forceinline__ unsigned short f2bf(float f) {   // RNE f32->bf16
    unsigned u = __float_as_uint(f);
    return (unsigned short)((u + 0x7fffu + ((u >> 16) & 1u)) >> 16);
}
__device__ __forceinline__ float bf2f(unsigned short h) {
    return __uint_as_float(((unsigned)h) << 16);
}

// ---------------------------------------------------------------- prep (tiny)
__global__ void k_prep(const float* __restrict__ bih_f, const float* __restrict__ bhh_f,
                       const float* __restrict__ bih_b, const float* __restrict__ bhh_b,
                       const float* __restrict__ We, const float* __restrict__ be,
                       const float* __restrict__ Wa, const float* __restrict__ ba,
                       float* __restrict__ ws) {
    const int N3 = 2 * 1024;     // bsum
    const int N4 = 65536;        // Wcat
    const int N5 = 128;          // bvec
    const int total = N3 + N4 + N5;
    for (int idx = blockIdx.x * blockDim.x + threadIdx.x; idx < total;
         idx += gridDim.x * blockDim.x) {
        int i = idx;
        if (i < N3) {
            int dir = i / 1024, r = i % 1024;
            ws[(dir ? O_BSUM_B : O_BSUM_F) + r] =
                (dir ? bih_b[r] + bhh_b[r] : bih_f[r] + bhh_f[r]);
            continue;
        }
        i -= N3;
        if (i < N4) {
            int k = i >> 7, n = i & 127;
            float v = 0.0f;
            if (n < 36)               v = Wa[n * WAS_ + k];
            else if (n < 72)          v = Wa[(n - 36) * WAS_ + KC_ + k];
            else if (n < 106)         v = We[(n - 72) * WES_ + k];
            ws[O_WCAT + i] = v;
            continue;
        }
        i -= N4;
        {
            float v = 0.0f;
            if (i < 36)               v = ba[i];
            else if (i >= 72 && i < 106) v = be[i - 72];
            ws[O_BVEC + i] = v;
        }
    }
}

// ------------------------------------------------- GEMM1 (MFMA bf16x3): z = x @ WihT + bsum
// 128x128 tile, 4 waves (2x2 of 64x64), mfma_f32_16x16x32_bf16, K=320 in 10 steps.
// SPLIT PRECISION: z = Xh*Wh + Xh*Wl + Xl*Wh (lo*lo omitted, ~1e-7 RMS) -- verified
// PASS at absmax 0.0039 (r5/r7/r10/r11/r12). Reads emb (ids-gathered) and Wih fp32
// DIRECTLY, casting hi/lo in-register while staging.
__global__ __launch_bounds__(256) void k_gemm1(const int* __restrict__ ids,
                                               const float* __restrict__ emb,
                                               const float* __restrict__ Wih_f,
                                               const float* __restrict__ Wih_b,
                                               float* __restrict__ ws) {
    __shared__ unsigned short Ah[128][40];
    __shared__ unsigned short Al[128][40];
    __shared__ unsigned short Bh[128][40];
    __shared__ unsigned short Bl[128][40];
    int dir = blockIdx.z;
    int m0 = blockIdx.y * 128;
    int n0 = blockIdx.x * 128;
    int tid = threadIdx.x;
    const float* bsv = ws + (dir ? O_BSUM_B : O_BSUM_F);

    int w = tid >> 6, lane = tid & 63;
    int wr = w >> 1, wc = w & 1;
    int lr = lane & 15, lk = lane >> 4;

    // staging: thread t -> LDS row t>>1, 16 elems at half (t&1)
    int sr = tid >> 1, sh = tid & 1;
    int gm = m0 + sr;
    int tt = gm >> 4, bb2 = gm & 15;
    int t_orig = dir ? (L_ - 1 - tt) : tt;
    int aid = ids[bb2 * L_ + t_orig];
    const float* arow = emb + (size_t)aid * D_;
    const float* brow = (dir ? Wih_b : Wih_f) + (size_t)(n0 + sr) * D_;
    int swb = sr * 80 + sh * 32;

    f32x4 acc[4][4] = {};
    for (int k0 = 0; k0 < KP_; k0 += 32) {
        int c0 = k0 + sh * 16;
        float fa[16], fb[16];
        if (c0 + 16 <= D_) {
#pragma unroll
            for (int q = 0; q < 4; q++) {
                float4 va = *(const float4*)(arow + c0 + q * 4);
                float4 vb = *(const float4*)(brow + c0 + q * 4);
                fa[q * 4 + 0] = va.x; fa[q * 4 + 1] = va.y;
                fa[q * 4 + 2] = va.z; fa[q * 4 + 3] = va.w;
                fb[q * 4 + 0] = vb.x; fb[q * 4 + 1] = vb.y;
                fb[q * 4 + 2] = vb.z; fb[q * 4 + 3] = vb.w;
            }
        } else {
#pragma unroll
            for (int e = 0; e < 16; e++) {
                int c = c0 + e;
                fa[e] = (c < D_) ? arow[c] : 0.0f;
                fb[e] = (c < D_) ? brow[c] : 0.0f;
            }
        }
        bf16x8 ah0, ah1, al0, al1, bh0, bh1, bl0, bl1;
#pragma unroll
        for (int e = 0; e < 8; e++) {
            unsigned short h;
            h = f2bf(fa[e]);     ah0[e] = (short)h; al0[e] = (short)f2bf(fa[e] - bf2f(h));
            h = f2bf(fa[e + 8]); ah1[e] = (short)h; al1[e] = (short)f2bf(fa[e + 8] - bf2f(h));
            h = f2bf(fb[e]);     bh0[e] = (short)h; bl0[e] = (short)f2bf(fb[e] - bf2f(h));
            h = f2bf(fb[e + 8]); bh1[e] = (short)h; bl1[e] = (short)f2bf(fb[e + 8] - bf2f(h));
        }
        *(bf16x8*)((char*)&Ah[0][0] + swb) = ah0;
        *(bf16x8*)((char*)&Ah[0][0] + swb + 16) = ah1;
        *(bf16x8*)((char*)&Al[0][0] + swb) = al0;
        *(bf16x8*)((char*)&Al[0][0] + swb + 16) = al1;
        *(bf16x8*)((char*)&Bh[0][0] + swb) = bh0;
        *(bf16x8*)((char*)&Bh[0][0] + swb + 16) = bh1;
        *(bf16x8*)((char*)&Bl[0][0] + swb) = bl0;
        *(bf16x8*)((char*)&Bl[0][0] + swb + 16) = bl1;
        __syncthreads();
        bf16x8 afh[4], afl[4], bfh[4], bfl[4];
#pragma unroll
        for (int mi = 0; mi < 4; mi++) {
            int rb = (wr * 64 + mi * 16 + lr) * 80 + lk * 16;
            afh[mi] = *(const bf16x8*)((const char*)&Ah[0][0] + rb);
            afl[mi] = *(const bf16x8*)((const char*)&Al[0][0] + rb);
        }
#pragma unroll
        for (int ni = 0; ni < 4; ni++) {
            int rb = (wc * 64 + ni * 16 + lr) * 80 + lk * 16;
            bfh[ni] = *(const bf16x8*)((const char*)&Bh[0][0] + rb);
            bfl[ni] = *(const bf16x8*)((const char*)&Bl[0][0] + rb);
        }
#pragma unroll
        for (int mi = 0; mi < 4; mi++)
#pragma unroll
            for (int ni = 0; ni < 4; ni++) {
                acc[mi][ni] = __builtin_amdgcn_mfma_f32_16x16x32_bf16(
                    afh[mi], bfh[ni], acc[mi][ni], 0, 0, 0);
                acc[mi][ni] = __builtin_amdgcn_mfma_f32_16x16x32_bf16(
                    afh[mi], bfl[ni], acc[mi][ni], 0, 0, 0);
                acc[mi][ni] = __builtin_amdgcn_mfma_f32_16x16x32_bf16(
                    afl[mi], bfh[ni], acc[mi][ni], 0, 0, 0);
            }
        __syncthreads();
    }
    float* zp = ws + O_ZPRE + (size_t)dir * 2048 * G4_;
    int crow = (lane >> 4) * 4;
#pragma unroll
    for (int ni = 0; ni < 4; ni++) {
        int n = n0 + wc * 64 + ni * 16 + lr;
        float bias = bsv[n];
#pragma unroll
        for (int mi = 0; mi < 4; mi++) {
            int mb = m0 + wr * 64 + mi * 16 + crow;
#pragma unroll
            for (int j = 0; j < 4; j++)
                zp[(size_t)(mb + j) * G4_ + n] = acc[mi][ni][j] + bias;
        }
    }
}

// ------------------------------------------------- LSTM: 128 blocks (r12 form, REVERTED)
// phys = g*32 + (dir*16+b). Thread rg owns 4 consecutive gate rows of one gate;
// kc==0 writes z to zbuf; wave0 does activation + ONE coalesced 512B publish;
// waves 1-3 poll self-tagged u64s (relaxed agent atomics).
// Protocol history: r1-r3 (L2 shortcuts) break or cost; r8 (fused producers)
// contends for CUs; r9 (poll train) forces vmcnt(0) over the train; r13 (2-block
// chains @1024thr) spills the 128-float weight set to scratch (VGPR cap 64 ->
// 4x regression). Sleep gradient: 6=201, 8=182, 10=180 (optimum). This 4-block
// 512-thread form at sleep(10) = 180us is the protocol floor. Kept byte-exact.
__global__ __launch_bounds__(512, 2) void k_lstm(float* __restrict__ ws,
                                                 const float* __restrict__ Whh_f,
                                                 const float* __restrict__ Whh_b) {
    int phys = blockIdx.x;
    int g    = phys >> 5;
    int cb   = phys & 31;
    int b    = cb & 15;
    int dir  = cb >> 4;
    int tid  = threadIdx.x;
    int rg   = tid >> 3;             // 0..63 -> 4 local gate rows each
    int kc   = tid & 7;              // 0..7  -> k chunk of 32

    const float* Whh  = dir ? Whh_b : Whh_f;
    const float* zpre = ws + O_ZPRE + (size_t)dir * 2048 * G4_;
    float* hid = ws + O_HIDDEN;
    unsigned long long* hx64 = (unsigned long long*)(ws + O_HX);

    __shared__ float h_sh[HIX(255) + 1 + 4];
    __shared__ float zbuf[256];

    int lr0  = rg << 2;
    int ggr0 = (lr0 >> 6) * 256 + g * 64 + (lr0 & 63);
    float4 w[4][8];
#pragma unroll
    for (int i = 0; i < 4; i++) {
        const float* wr = Whh + (size_t)(ggr0 + i) * H_ + (kc << 5);
#pragma unroll
        for (int c = 0; c < 8; c++) w[i][c] = *(const float4*)(wr + (c << 2));
    }
    for (int k = tid; k < HIX(255) + 1 + 4; k += 512) h_sh[k] = 0.0f;
    float c_state = 0.0f;
    float4 zv = make_float4(0.f, 0.f, 0.f, 0.f);
    if (kc == 0) zv = *(const float4*)(zpre + (size_t)(0 * B_ + b) * G4_ + ggr0);
    __syncthreads();

    for (int s = 0; s < L_; s++) {
        float4 zn = make_float4(0.f, 0.f, 0.f, 0.f);
        if (kc == 0 && s + 1 < L_)
            zn = *(const float4*)(zpre + (size_t)((s + 1) * B_ + b) * G4_ + ggr0);
        float a0 = 0.f, a1 = 0.f, a2 = 0.f, a3 = 0.f;
        const float* hp = &h_sh[kc * 36];
#pragma unroll
        for (int c = 0; c < 8; c++) {
            float4 hv = *(const float4*)(hp + (c << 2));
            a0 = fmaf(w[0][c].x, hv.x, a0); a0 = fmaf(w[0][c].y, hv.y, a0);
            a0 = fmaf(w[0][c].z, hv.z, a0); a0 = fmaf(w[0][c].w, hv.w, a0);
            a1 = fmaf(w[1][c].x, hv.x, a1); a1 = fmaf(w[1][c].y, hv.y, a1);
            a1 = fmaf(w[1][c].z, hv.z, a1); a1 = fmaf(w[1][c].w, hv.w, a1);
            a2 = fmaf(w[2][c].x, hv.x, a2); a2 = fmaf(w[2][c].y, hv.y, a2);
            a2 = fmaf(w[2][c].z, hv.z, a2); a2 = fmaf(w[2][c].w, hv.w, a2);
            a3 = fmaf(w[3][c].x, hv.x, a3); a3 = fmaf(w[3][c].y, hv.y, a3);
            a3 = fmaf(w[3][c].z, hv.z, a3); a3 = fmaf(w[3][c].w, hv.w, a3);
        }
#pragma unroll
        for (int m = 1; m < 8; m <<= 1) {
            a0 += __shfl_xor(a0, m); a1 += __shfl_xor(a1, m);
            a2 += __shfl_xor(a2, m); a3 += __shfl_xor(a3, m);
        }
        if (kc == 0) {
            float4 z4;
            z4.x = a0 + zv.x; z4.y = a1 + zv.y; z4.z = a2 + zv.z; z4.w = a3 + zv.w;
            *(float4*)&zbuf[lr0] = z4;
        }
        zv = zn;
        BARRIER_LGKM();
        int par = (s + 1) & 1;
        if (tid < 64) {
            float fi = fsig(zbuf[tid]);
            float ff = fsig(zbuf[tid + 64]);
            float gg = ftanh(zbuf[tid + 128]);
            float fo = fsig(zbuf[tid + 192]);
            c_state = ff * c_state + fi * gg;
            float h = fo * ftanh(c_state);
            int hr = g * 64 + tid;
            // publish FIRST: visibility latency is the critical path
            if (s + 1 < L_) {
                unsigned long long pk =
                    ((unsigned long long)(unsigned)(s + 1) << 32) | (unsigned)__float_as_uint(h);
                __hip_atomic_store(&hx64[(par << 13) + (phys << 6) + tid], pk,
                                   __ATOMIC_RELAXED, __HIP_MEMORY_SCOPE_AGENT);
            }
            h_sh[HIX(hr)] = h;
            int t_orig = dir ? (L_ - 1 - s) : s;
            hid[(size_t)(t_orig * B_ + b) * KC_ + dir * H_ + hr] = h;
        }
        if (tid >= 64 && tid < 256 && s + 1 < L_) {
            int which = tid >> 6;                 // 1..3
            int sg = (g + which) & 3;
            int sb = cb | (sg << 5);              // sibling physical block id
            int u  = tid & 63;
            const unsigned long long* wp = &hx64[(par << 13) + (sb << 6) + u];
            unsigned long long v;
            int cnt = 0;
            // phase-align the first poll with publish visibility
            __builtin_amdgcn_s_sleep(10);
            do {
                v = __hip_atomic_load(wp, __ATOMIC_RELAXED, __HIP_MEMORY_SCOPE_AGENT);
            } while ((int)(v >> 32) < s + 1 && ++cnt < (1 << 20));
            h_sh[HIX(sg * 64 + u)] = __uint_as_float((unsigned)v);
        }
        BARRIER_LGKM();
    }
}

// ------------------------------------------------- GEMM2: P = hidden @ Wcat + bvec
__global__ __launch_bounds__(256) void k_gemm2(float* __restrict__ ws) {
    __shared__ float As[16][64];
    __shared__ float Bs[16][64];
    int m0 = blockIdx.y * 64;
    int n0 = blockIdx.x * 64;
    int tid = threadIdx.x;
    const float* Ap = ws + O_HIDDEN;
    const float* Bp = ws + O_WCAT;
    const float* bv = ws + O_BVEC;
    float acc[4][4] = {};
    int a_m = tid >> 2, a_k = (tid & 3) << 2;
    int b_k = tid >> 4, b_n = (tid & 15) << 2;
    int ty = tid >> 4, tx = tid & 15;
    const float* arow = Ap + (size_t)(m0 + a_m) * KC_;
    for (int k0 = 0; k0 < KC_; k0 += 16) {
        float4 av = *(const float4*)(arow + k0 + a_k);
        float4 bvv = *(const float4*)(Bp + (size_t)(k0 + b_k) * NCAT_ + n0 + b_n);
        As[a_k + 0][a_m] = av.x; As[a_k + 1][a_m] = av.y;
        As[a_k + 2][a_m] = av.z; As[a_k + 3][a_m] = av.w;
        *(float4*)&Bs[b_k][b_n] = bvv;
        __syncthreads();
#pragma unroll
        for (int kk = 0; kk < 16; kk++) {
            float4 a4 = *(const float4*)&As[kk][ty * 4];
            float4 b4 = *(const float4*)&Bs[kk][tx * 4];
            acc[0][0] = fmaf(a4.x, b4.x, acc[0][0]); acc[0][1] = fmaf(a4.x, b4.y, acc[0][1]);
            acc[0][2] = fmaf(a4.x, b4.z, acc[0][2]); acc[0][3] = fmaf(a4.x, b4.w, acc[0][3]);
            acc[1][0] = fmaf(a4.y, b4.x, acc[1][0]); acc[1][1] = fmaf(a4.y, b4.y, acc[1][1]);
            acc[1][2] = fmaf(a4.y, b4.z, acc[1][2]); acc[1][3] = fmaf(a4.y, b4.w, acc[1][3]);
            acc[2][0] = fmaf(a4.z, b4.x, acc[2][0]); acc[2][1] = fmaf(a4.z, b4.y, acc[2][1]);
            acc[2][2] = fmaf(a4.z, b4.z, acc[2][2]); acc[2][3] = fmaf(a4.z, b4.w, acc[2][3]);
            acc[3][0] = fmaf(a4.w, b4.x, acc[3][0]); acc[3][1] = fmaf(a4.w, b4.y, acc[3][1]);
            acc[3][2] = fmaf(a4.w, b4.z, acc[3][2]); acc[3][3] = fmaf(a4.w, b4.w, acc[3][3]);
        }
        __syncthreads();
    }
    float4 bias = *(const float4*)(bv + n0 + tx * 4);
    float* Pp = ws + O_P + (size_t)m0 * NCAT_;
#pragma unroll
    for (int i = 0; i < 4; i++) {
        float4 o;
        o.x = acc[i][0] + bias.x; o.y = acc[i][1] + bias.y;
        o.z = acc[i][2] + bias.z; o.w = acc[i][3] + bias.w;
        *(float4*)(Pp + (size_t)(ty * 4 + i) * NCAT_ + n0 + tx * 4) = o;
    }
}

// ------------------------------------------------- fused decoder (r10 form)
// block 0: event chains (16 waves), publishes self-tagged preds evtag[b][i] = ((i+1)<<8)|p;
//   depth-3 P-row prefetch (r10: -5us).
// blocks 1..128: 16 argument chains each; tag reads amortized via a cached 64-slot
// window (ONE agent load per 64 steps per lane + shfl). Tag polls use s_sleep
// backoff on miss. Arg chains keep depth-2 (wave parallelism hides their latency).
__global__ __launch_bounds__(1024) void k_dec(const float* __restrict__ We,
                                              const float* __restrict__ Wa,
                                              float* __restrict__ ws, float* __restrict__ out) {
    const float* P = ws + O_P;
    int* evtag = (int*)(ws + O_EVTAG);   // [16][128]
    int lane = threadIdx.x & 63;
    if (blockIdx.x == 0) {
        int b = threadIdx.x >> 6;
        float Cg = 0.0f;
        unsigned long long gmask = 0ull;
        float pv = (lane < E_) ? P[(size_t)(0 * B_ + b) * NCAT_ + 72 + lane] : 0.0f;
        float p1 = (lane < E_) ? P[(size_t)(1 * B_ + b) * NCAT_ + 72 + lane] : 0.0f;
        float p2 = (lane < E_) ? P[(size_t)(2 * B_ + b) * NCAT_ + 72 + lane] : 0.0f;
        for (int i = 0; i < L_; i++) {
            float p3 = 0.0f;
            if (i + 3 < L_ && lane < E_) p3 = P[(size_t)((i + 3) * B_ + b) * NCAT_ + 72 + lane];
            float v = (lane < E_) ? (pv + Cg) : -INFINITY;
            float mv = v;
            int mi = (lane < E_) ? lane : 0x7fffffff;
#pragma unroll
            for (int off = 32; off; off >>= 1) {
                float ov = __shfl_down(mv, off);
                int oi = __shfl_down(mi, off);
                if (ov > mv || (ov == mv && oi < mi)) { mv = ov; mi = oi; }
            }
            int p = __shfl(mi, 0);
            if (lane == 0)
                __hip_atomic_store(&evtag[b * L_ + i], ((i + 1) << 8) | p,
                                   __ATOMIC_RELAXED, __HIP_MEMORY_SCOPE_AGENT);
            if (lane < E_) out[(size_t)(b * L_ + i) * E_ + lane] = v;
            if (p > 0) {
                unsigned long long bit = 1ull << (p - 1);
                if (!(gmask & bit)) {
                    gmask |= bit;
                    if (lane < E_) Cg += We[lane * WES_ + 2 * H_ + (p - 1)];
                }
            }
            pv = p1; p1 = p2; p2 = p3;
        }
    } else {
        int w = ((blockIdx.x - 1) << 4) + (threadIdx.x >> 6);  // 0..2047
        int b = w >> 7, j = w & 127;
        float* outa = out + (size_t)B_ * L_ * E_;
        float C = 0.0f;
        if (lane < A_) C = P[(size_t)(j * B_ + b) * NCAT_ + lane];
        unsigned long long ga = 0ull, gta = 0ull;
        float tv = (lane < A_) ? P[(size_t)(0 * B_ + b) * NCAT_ + 36 + lane] : 0.0f;
        float t1 = (lane < A_) ? P[(size_t)(1 * B_ + b) * NCAT_ + 36 + lane] : 0.0f;
        int myv = (int)0x80000000;   // cached tag word for window slot `lane`
        for (int i = 0; i < L_; i++) {
            float t2 = 0.0f;
            if (i + 2 < L_ && lane < A_) t2 = P[(size_t)((i + 2) * B_ + b) * NCAT_ + 36 + lane];
            int w0 = i & ~63;
            if ((i & 63) == 0)
                myv = __hip_atomic_load(&evtag[b * L_ + w0 + lane],
                                        __ATOMIC_RELAXED, __HIP_MEMORY_SCOPE_AGENT);
            int tv_tag = __shfl(myv, i & 63);
            if ((tv_tag >> 8) < i + 1) {   // wave-uniform miss: backoff poll
                int cnt = 0;
                do {
                    __builtin_amdgcn_s_sleep(1);
                    myv = __hip_atomic_load(&evtag[b * L_ + w0 + lane],
                                            __ATOMIC_RELAXED, __HIP_MEMORY_SCOPE_AGENT);
                    tv_tag = __shfl(myv, i & 63);
                } while ((tv_tag >> 8) < i + 1 && ++cnt < (1 << 18));
            }
            int ev = tv_tag & 0xff;
            float v = (lane < A_) ? (C + tv) : -INFINITY;
            float mv = v;
            int mi = (lane < A_) ? lane : 0x7fffffff;
#pragma unroll
            for (int off = 32; off; off >>= 1) {
                float ov = __shfl_down(mv, off);
                int oi = __shfl_down(mi, off);
                if (ov > mv || (ov == mv && oi < mi)) { mv = ov; mi = oi; }
            }
            int p = __shfl(mi, 0);
            if (lane < A_) outa[(size_t)((b * L_ + i) * L_ + j) * A_ + lane] = v;
            if (ev > 0 && p > 0) {
                unsigned long long bq = 1ull << (ev - 1);
                if (!(gta & bq)) {
                    gta |= bq;
                    if (lane < A_) C += Wa[lane * WAS_ + 4 * H_ + A_ - 1 + (ev - 1)];
                }
                unsigned long long br = 1ull << (p - 1);
                if (!(ga & br)) {
                    ga |= br;
                    if (lane < A_) C += Wa[lane * WAS_ + 4 * H_ + (p - 1)];
                }
            }
            tv = t1; t1 = t2;
        }
    }
}

// ----------------------------------------------------------------
extern "C" void kernel_launch(void* const* d_in, const int* in_sizes, int n_in,
                              void* d_out, int out_size, void* d_ws, size_t ws_size,
                              hipStream_t stream) {
    (void)in_sizes; (void)n_in; (void)out_size; (void)ws_size;
    const int*   ids   = (const int*)d_in[0];
    const float* emb   = (const float*)d_in[1];
    const float* Wih_f = (const float*)d_in[2];
    const float* Whh_f = (const float*)d_in[3];
    const float* bih_f = (const float*)d_in[4];
    const float* bhh_f = (const float*)d_in[5];
    const float* Wih_b = (const float*)d_in[6];
    const float* Whh_b = (const float*)d_in[7];
    const float* bih_b = (const float*)d_in[8];
    const float* bhh_b = (const float*)d_in[9];
    const float* We    = (const float*)d_in[10];
    const float* be    = (const float*)d_in[11];
    const float* Wa    = (const float*)d_in[12];
    const float* ba    = (const float*)d_in[13];
    float* out = (float*)d_out;
    float* ws  = (float*)d_ws;

    hipLaunchKernelGGL(k_prep, dim3(64), dim3(256), 0, stream,
                       bih_f, bhh_f, bih_b, bhh_b, We, be, Wa, ba, ws);
    hipLaunchKernelGGL(k_gemm1, dim3(8, 16, 2), dim3(256), 0, stream,
                       ids, emb, Wih_f, Wih_b, ws);
    hipLaunchKernelGGL(k_lstm, dim3(128), dim3(512), 0, stream, ws, Whh_f, Whh_b);
    hipLaunchKernelGGL(k_gemm2, dim3(2, 32, 1), dim3(256), 0, stream, ws);
    hipLaunchKernelGGL(k_dec, dim3(129), dim3(1024), 0, stream, We, Wa, ws, out);
}